// Round 7
// baseline (180.545 us; speedup 1.0000x reference)
//
#include <hip/hip_runtime.h>

// Problem: B=32, N=128, T=96, H=64, TF=24. All I/O float32.
// A_norm = ones(N,N)/N => every GCN output is the node-mean (node-uniform);
// model collapses to per-batch H-vectors. Node dim appears only in the
// initial mean and the final broadcast.
//
// R6 post-mortem: compiler caps VGPRs ~132; 128-float per-wave weight arrays
// can't be made resident (pin => scratch spills, 83->107us). Also the 1-wave
// ODE is issue-bound (~39us minimum). This version splits every ODE matvec
// across the 4 waves (16 rows each => 16-float arrays, trivially resident),
// combining partials via double-buffered LDS + barrier. Phase 1 is split in
// two passes so each needs only one 64-float array (~85 VGPR peak).

#define BN 32
#define NN 128
#define TT 96
#define HH 64
#define TFC 24

__device__ __forceinline__ float rdl(float v, int l) {
    return __int_as_float(__builtin_amdgcn_readlane(__float_as_int(v), l));
}
__device__ __forceinline__ float fast_tanh(float x) {
    x = fminf(fmaxf(x, -15.f), 15.f);
    float e = __expf(2.f * x);
    return (e - 1.f) / (e + 1.f);
}
__device__ __forceinline__ float fast_sigmoid(float x) {
    return 1.f / (1.f + __expf(-x));
}
__device__ __forceinline__ float wave_sum(float v) {
#pragma unroll
    for (int off = 32; off > 0; off >>= 1) v += __shfl_xor(v, off, 64);
    return v;
}
__device__ __forceinline__ float wave_max(float v) {
#pragma unroll
    for (int off = 32; off > 0; off >>= 1) v = fmaxf(v, __shfl_xor(v, off, 64));
    return v;
}

__global__ __launch_bounds__(256) void fused_kernel(
    const float* __restrict__ x,    const float* __restrict__ Ws1,
    const float* __restrict__ bs1,  const float* __restrict__ Ws2,
    const float* __restrict__ bs2,  const float* __restrict__ Wa1,
    const float* __restrict__ ba1,  const float* __restrict__ Wa2,
    const float* __restrict__ Wih,  const float* __restrict__ bih,
    const float* __restrict__ bhh,  const float* __restrict__ Wo1,
    const float* __restrict__ bo1p, const float* __restrict__ Wo2,
    const float* __restrict__ bo2p, const float* __restrict__ Wout,
    const float* __restrict__ boutp, float* __restrict__ out)
{
    const int tid  = threadIdx.x;
    const int lane = tid & 63;
    const int w    = tid >> 6;
    const int b    = blockIdx.x;

    __shared__ float xbar[TT];
    __shared__ float h2s[TT][HH];
    __shared__ float atts[TT];
    __shared__ float part[2][4][HH];   // double-buffered matvec partials

    // ---- phase 0: xbar[t] = mean_n x[b,n,t] ----
    if (tid < TT) {
        const float* xb = x + (size_t)b * NN * TT + tid;
        float s = 0.f;
#pragma unroll
        for (int n = 0; n < NN; ++n) s += xb[n * TT];
        xbar[tid] = s * (1.f / 128.f);
    }

    {   // ---- phase 1a: h2 for all t (needs only ws2c[64]) ----
        const float ws1l = Ws1[lane];
        const float bs1l = bs1[lane];
        const float bs2l = bs2[lane];
        float ws2c[HH];
#pragma unroll
        for (int h = 0; h < HH; ++h) ws2c[h] = Ws2[h * HH + lane];
        __syncthreads();   // xbar ready
#pragma unroll 1
        for (int i = 0; i < TT / 4; ++i) {
            const int t = w * (TT / 4) + i;
            const float s = xbar[t];
            const float h1 = fmaxf(fmaf(s, ws1l, bs1l), 0.f);  // lane = h
            float a0 = bs2l, a1 = 0.f, a2 = 0.f, a3 = 0.f;
#pragma unroll
            for (int h = 0; h < HH; h += 4) {
                a0 = fmaf(rdl(h1, h),     ws2c[h],     a0);
                a1 = fmaf(rdl(h1, h + 1), ws2c[h + 1], a1);
                a2 = fmaf(rdl(h1, h + 2), ws2c[h + 2], a2);
                a3 = fmaf(rdl(h1, h + 3), ws2c[h + 3], a3);
            }
            h2s[t][lane] = fmaxf((a0 + a1) + (a2 + a3), 0.f);
        }
    }
    {   // ---- phase 1b: attention logits (needs only wa1c[64]) ----
        const float ba1l = ba1[lane];
        const float wa2l = Wa2[lane];
        float wa1c[HH];
#pragma unroll
        for (int h = 0; h < HH; ++h) wa1c[h] = Wa1[h * HH + lane];
        __syncthreads();   // h2s ready (own wave's writes + others')
#pragma unroll 1
        for (int i = 0; i < TT / 4; ++i) {
            const int t = w * (TT / 4) + i;
            const float h2v = h2s[t][lane];
            float a0 = ba1l, a1 = 0.f, a2 = 0.f, a3 = 0.f;
#pragma unroll
            for (int h = 0; h < HH; h += 4) {
                a0 = fmaf(rdl(h2v, h),     wa1c[h],     a0);
                a1 = fmaf(rdl(h2v, h + 1), wa1c[h + 1], a1);
                a2 = fmaf(rdl(h2v, h + 2), wa1c[h + 2], a2);
                a3 = fmaf(rdl(h2v, h + 3), wa1c[h + 3], a3);
            }
            const float g = fast_tanh((a0 + a1) + (a2 + a3));
            const float att = wave_sum(g * wa2l);   // ba2: shift-invariant
            if (lane == 0) atts[t] = att;
        }
    }
    __syncthreads();   // atts ready

    // ---- phase 2 (ALL waves redundantly => replicated identical state) ----
    const float a0s = atts[lane];
    const float a1s = (lane < TT - 64) ? atts[64 + lane] : -1e30f;
    const float m = wave_max(fmaxf(a0s, a1s));
    const float e0 = __expf(a0s - m);
    const float e1 = (lane < TT - 64) ? __expf(a1s - m) : 0.f;
    const float inv = 1.f / wave_sum(e0 + e1);
    const float q0 = e0 * inv;
    const float q1 = e1 * inv;

    float nf = 0.f;
#pragma unroll
    for (int t = 0; t < 64; ++t) nf = fmaf(rdl(q0, t), h2s[t][lane], nf);
#pragma unroll
    for (int t = 0; t < 32; ++t) nf = fmaf(rdl(q1, t), h2s[64 + t][lane], nf);

    // one-step GRU, h0=0 (W_hh matmul vanishes; b_hh biases remain)
    float gr = bih[lane];
    float gz = bih[64 + lane];
    float gn = bih[128 + lane];
#pragma unroll
    for (int j = 0; j < HH; j += 4) {
        const float4 wr = *(const float4*)&Wih[(size_t)lane * HH + j];
        const float4 wz = *(const float4*)&Wih[(size_t)(64 + lane) * HH + j];
        const float4 wn = *(const float4*)&Wih[(size_t)(128 + lane) * HH + j];
        const float n0 = rdl(nf, j), n1 = rdl(nf, j + 1);
        const float n2 = rdl(nf, j + 2), n3 = rdl(nf, j + 3);
        gr += n0 * wr.x + n1 * wr.y + n2 * wr.z + n3 * wr.w;
        gz += n0 * wz.x + n1 * wz.y + n2 * wz.z + n3 * wz.w;
        gn += n0 * wn.x + n1 * wn.y + n2 * wn.z + n3 * wn.w;
    }
    const float r = fast_sigmoid(gr + bhh[lane]);
    const float z = fast_sigmoid(gz + bhh[64 + lane]);
    const float n = fast_tanh(gn + r * bhh[128 + lane]);
    float y = (1.f - z) * n;   // identical in all 4 waves

    // ---- phase 3: ODE. Wave w owns rows [16w, 16w+16) of W1 and W2. ----
    const int base = 16 * w;
    float w1c[16], w2c[16];
#pragma unroll
    for (int j = 0; j < 16; ++j) {
        w1c[j] = Wo1[(base + j) * HH + lane];
        w2c[j] = Wo2[(base + j) * HH + lane];
    }
    const float bo1 = bo1p[lane];
    const float bo2 = bo2p[lane];
    const float wo  = Wout[lane];
    const float bo  = boutp[0];

    // f(u): each wave computes a 16-row partial; LDS-combine; all waves get
    // the full result (identical). 2 barriers per f_eval, parity-buffered.
    auto f_eval = [&](float u) -> float {
        float c0 = 0.f, c1 = 0.f, c2 = 0.f, c3 = 0.f;
#pragma unroll
        for (int j = 0; j < 16; j += 4) {
            c0 = fmaf(rdl(u, base + j),     w1c[j],     c0);
            c1 = fmaf(rdl(u, base + j + 1), w1c[j + 1], c1);
            c2 = fmaf(rdl(u, base + j + 2), w1c[j + 2], c2);
            c3 = fmaf(rdl(u, base + j + 3), w1c[j + 3], c3);
        }
        part[0][w][lane] = (c0 + c1) + (c2 + c3);
        __syncthreads();
        const float v = fast_tanh(part[0][0][lane] + part[0][1][lane] +
                                  part[0][2][lane] + part[0][3][lane] + bo1);
        c0 = 0.f; c1 = 0.f; c2 = 0.f; c3 = 0.f;
#pragma unroll
        for (int j = 0; j < 16; j += 4) {
            c0 = fmaf(rdl(v, base + j),     w2c[j],     c0);
            c1 = fmaf(rdl(v, base + j + 1), w2c[j + 1], c1);
            c2 = fmaf(rdl(v, base + j + 2), w2c[j + 2], c2);
            c3 = fmaf(rdl(v, base + j + 3), w2c[j + 3], c3);
        }
        part[1][w][lane] = (c0 + c1) + (c2 + c3);
        __syncthreads();
        return fast_tanh(part[1][0][lane] + part[1][1][lane] +
                         part[1][2][lane] + part[1][3][lane] + bo2);
    };

    // output head: p uniform after wave_sum; waves 0,1 store 64 nodes each.
    float* ob = out + (size_t)b * NN * TFC;
    {
        const float p = wave_sum(y * wo) + bo;     // traj[0] = hidden
        if (w < 2) ob[(w * 64 + lane) * TFC] = p;
    }

    const float dt = (float)(24.0 / 23.0);
    const float third = 1.f / 3.f;

#pragma unroll 1
    for (int st = 0; st < TFC - 1; ++st) {
        const float k1 = f_eval(y);
        const float k2 = f_eval(y + dt * k1 * third);
        const float k3 = f_eval(y + dt * (k2 - k1 * third));
        const float k4 = f_eval(y + dt * (k1 - k2 + k3));
        y = y + dt * (k1 + 3.f * (k2 + k3) + k4) * 0.125f;
        const float p = wave_sum(y * wo) + bo;
        if (w < 2) ob[(w * 64 + lane) * TFC + st + 1] = p;
    }
}

extern "C" void kernel_launch(void* const* d_in, const int* in_sizes, int n_in,
                              void* d_out, int out_size, void* d_ws, size_t ws_size,
                              hipStream_t stream) {
    (void)in_sizes; (void)n_in; (void)d_ws; (void)ws_size; (void)out_size;
    const float* x    = (const float*)d_in[0];
    const float* Ws1  = (const float*)d_in[1];
    const float* bs1  = (const float*)d_in[2];
    const float* Ws2  = (const float*)d_in[3];
    const float* bs2  = (const float*)d_in[4];
    const float* Wa1  = (const float*)d_in[5];
    const float* ba1  = (const float*)d_in[6];
    const float* Wa2  = (const float*)d_in[7];
    // d_in[8]  = ba2  : unused (softmax shift-invariant)
    const float* Wih  = (const float*)d_in[9];
    // d_in[10] = W_hh : unused (h0 = 0)
    const float* bih  = (const float*)d_in[11];
    const float* bhh  = (const float*)d_in[12];
    const float* Wo1  = (const float*)d_in[13];
    const float* bo1  = (const float*)d_in[14];
    const float* Wo2  = (const float*)d_in[15];
    const float* bo2  = (const float*)d_in[16];
    const float* Wout = (const float*)d_in[17];
    const float* bout = (const float*)d_in[18];

    fused_kernel<<<dim3(BN), dim3(256), 0, stream>>>(
        x, Ws1, bs1, Ws2, bs2, Wa1, ba1, Wa2,
        Wih, bih, bhh, Wo1, bo1, Wo2, bo2, Wout, bout,
        (float*)d_out);
}

// Round 8
// 169.417 us; speedup vs baseline: 1.0657x; 1.0657x over previous
//
#include <hip/hip_runtime.h>

// Problem: B=32, N=128, T=96, H=64, TF=24. All I/O float32.
// A_norm = ones(N,N)/N => every GCN output is the node-mean (node-uniform);
// model collapses to per-batch H-vectors. Node dim appears only in the
// initial mean and the final broadcast.
//
// R5-R7 post-mortems: (1) allocator caps VGPRs ~132 and sinks/spills any
// 64-float-per-matrix weight array => fp32 register residency impossible;
// (2) block barriers in the sequential ODE cost ~2x the compute they wrap.
// This version: ODE weights staged ONCE into LDS (32KB, coalesced float4);
// single-wave ODE reads them via ds_read_b32 at wave-uniform base + lane*4
// (stride-1 => 2-way bank aliasing = free; h*256 fits the 16-bit ds imm =>
// no address math). Per MAC: ds_read + readlane + fmac. No barriers, no
// global loads, no allocator dependence in the chain.

#define BN 32
#define NN 128
#define TT 96
#define HH 64
#define TFC 24

__device__ __forceinline__ float rdl(float v, int l) {
    return __int_as_float(__builtin_amdgcn_readlane(__float_as_int(v), l));
}
__device__ __forceinline__ float fast_tanh(float x) {
    x = fminf(fmaxf(x, -15.f), 15.f);
    float e = __expf(2.f * x);
    return (e - 1.f) / (e + 1.f);
}
__device__ __forceinline__ float fast_sigmoid(float x) {
    return 1.f / (1.f + __expf(-x));
}
__device__ __forceinline__ float wave_sum(float v) {
#pragma unroll
    for (int off = 32; off > 0; off >>= 1) v += __shfl_xor(v, off, 64);
    return v;
}
__device__ __forceinline__ float wave_max(float v) {
#pragma unroll
    for (int off = 32; off > 0; off >>= 1) v = fmaxf(v, __shfl_xor(v, off, 64));
    return v;
}

__global__ __launch_bounds__(256) void fused_kernel(
    const float* __restrict__ x,    const float* __restrict__ Ws1,
    const float* __restrict__ bs1,  const float* __restrict__ Ws2,
    const float* __restrict__ bs2,  const float* __restrict__ Wa1,
    const float* __restrict__ ba1,  const float* __restrict__ Wa2,
    const float* __restrict__ Wih,  const float* __restrict__ bih,
    const float* __restrict__ bhh,  const float* __restrict__ Wo1,
    const float* __restrict__ bo1p, const float* __restrict__ Wo2,
    const float* __restrict__ bo2p, const float* __restrict__ Wout,
    const float* __restrict__ boutp, float* __restrict__ out)
{
    const int tid  = threadIdx.x;
    const int lane = tid & 63;
    const int w    = tid >> 6;
    const int b    = blockIdx.x;

    __shared__ float xbar[TT];
    __shared__ float h2s[TT][HH];
    __shared__ float atts[TT];
    __shared__ float wo1_l[HH * HH];   // [h][j] : ODE layer-1 weights, 16KB
    __shared__ float wo2_l[HH * HH];   // [h][j] : ODE layer-2 weights, 16KB

    // ---- stage ODE weights into LDS (coalesced float4, all 256 threads) ----
#pragma unroll
    for (int i = 0; i < 4; ++i) {
        const int idx = (i * 256 + tid) * 4;                 // float index
        *(float4*)&wo1_l[idx] = *(const float4*)&Wo1[idx];
        *(float4*)&wo2_l[idx] = *(const float4*)&Wo2[idx];
    }

    // ---- phase 0: xbar[t] = mean_n x[b,n,t] ----
    if (tid < TT) {
        const float* xb = x + (size_t)b * NN * TT + tid;
        float s = 0.f;
#pragma unroll
        for (int n = 0; n < NN; ++n) s += xb[n * TT];
        xbar[tid] = s * (1.f / 128.f);
    }

    {   // ---- phase 1: spatial GCN + attention logits (register weights;
        //      reload-sinking is fine here: 24 iters amortize L1 hits) ----
        const float ws1l = Ws1[lane];
        const float bs1l = bs1[lane];
        const float bs2l = bs2[lane];
        const float ba1l = ba1[lane];
        const float wa2l = Wa2[lane];
        float ws2c[HH], wa1c[HH];
#pragma unroll
        for (int h = 0; h < HH; ++h) {
            ws2c[h] = Ws2[h * HH + lane];
            wa1c[h] = Wa1[h * HH + lane];
        }
        __syncthreads();   // barrier 1: xbar + staged weights ready

#pragma unroll 1
        for (int i = 0; i < TT / 4; ++i) {
            const int t = w * (TT / 4) + i;
            const float s = xbar[t];
            const float h1 = fmaxf(fmaf(s, ws1l, bs1l), 0.f);  // lane = h
            float a0 = bs2l, a1 = 0.f, a2 = 0.f, a3 = 0.f;
#pragma unroll
            for (int h = 0; h < HH; h += 4) {
                a0 = fmaf(rdl(h1, h),     ws2c[h],     a0);
                a1 = fmaf(rdl(h1, h + 1), ws2c[h + 1], a1);
                a2 = fmaf(rdl(h1, h + 2), ws2c[h + 2], a2);
                a3 = fmaf(rdl(h1, h + 3), ws2c[h + 3], a3);
            }
            const float h2v = fmaxf((a0 + a1) + (a2 + a3), 0.f);
            h2s[t][lane] = h2v;

            a0 = ba1l; a1 = 0.f; a2 = 0.f; a3 = 0.f;
#pragma unroll
            for (int h = 0; h < HH; h += 4) {
                a0 = fmaf(rdl(h2v, h),     wa1c[h],     a0);
                a1 = fmaf(rdl(h2v, h + 1), wa1c[h + 1], a1);
                a2 = fmaf(rdl(h2v, h + 2), wa1c[h + 2], a2);
                a3 = fmaf(rdl(h2v, h + 3), wa1c[h + 3], a3);
            }
            const float g = fast_tanh((a0 + a1) + (a2 + a3));
            const float att = wave_sum(g * wa2l);   // ba2: shift-invariant
            if (lane == 0) atts[t] = att;
        }
    }
    __syncthreads();   // barrier 2: h2s, atts ready

    if (w != 0) return;   // waves 1-3 retire; wave 0 owns the LDS pipe

    // ================= wave 0 only: softmax + nf + GRU + ODE =================
    const float a0s = atts[lane];
    const float a1s = (lane < TT - 64) ? atts[64 + lane] : -1e30f;
    const float m = wave_max(fmaxf(a0s, a1s));
    const float e0 = __expf(a0s - m);
    const float e1 = (lane < TT - 64) ? __expf(a1s - m) : 0.f;
    const float inv = 1.f / wave_sum(e0 + e1);
    const float q0 = e0 * inv;
    const float q1 = e1 * inv;

    float nf = 0.f;
#pragma unroll
    for (int t = 0; t < 64; ++t) nf = fmaf(rdl(q0, t), h2s[t][lane], nf);
#pragma unroll
    for (int t = 0; t < 32; ++t) nf = fmaf(rdl(q1, t), h2s[64 + t][lane], nf);

    // one-step GRU, h0=0 (W_hh matmul vanishes; b_hh biases remain)
    float gr = bih[lane];
    float gz = bih[64 + lane];
    float gn = bih[128 + lane];
#pragma unroll
    for (int j = 0; j < HH; j += 4) {
        const float4 wr = *(const float4*)&Wih[(size_t)lane * HH + j];
        const float4 wz = *(const float4*)&Wih[(size_t)(64 + lane) * HH + j];
        const float4 wn = *(const float4*)&Wih[(size_t)(128 + lane) * HH + j];
        const float n0 = rdl(nf, j), n1 = rdl(nf, j + 1);
        const float n2 = rdl(nf, j + 2), n3 = rdl(nf, j + 3);
        gr += n0 * wr.x + n1 * wr.y + n2 * wr.z + n3 * wr.w;
        gz += n0 * wz.x + n1 * wz.y + n2 * wz.z + n3 * wz.w;
        gn += n0 * wn.x + n1 * wn.y + n2 * wn.z + n3 * wn.w;
    }
    const float r = fast_sigmoid(gr + bhh[lane]);
    const float z = fast_sigmoid(gz + bhh[64 + lane]);
    const float n = fast_tanh(gn + r * bhh[128 + lane]);
    float y = (1.f - z) * n;

    const float bo1 = bo1p[lane];
    const float bo2 = bo2p[lane];
    const float wo  = Wout[lane];
    const float bo  = boutp[0];

    // f(u) = tanh( tanh(u@W1+b1) @ W2 + b2 )
    // Weights from LDS: address = uniform base + lane*4, imm offset h*256
    // => 1 ds_read_b32 + 1 readlane + 1 fmac per MAC. No barriers.
    auto f_eval = [&](float u) -> float {
        float c0 = bo1, c1 = 0.f, c2 = 0.f, c3 = 0.f;
#pragma unroll
        for (int h = 0; h < HH; h += 4) {
            c0 = fmaf(rdl(u, h),     wo1_l[(h    ) * HH + lane], c0);
            c1 = fmaf(rdl(u, h + 1), wo1_l[(h + 1) * HH + lane], c1);
            c2 = fmaf(rdl(u, h + 2), wo1_l[(h + 2) * HH + lane], c2);
            c3 = fmaf(rdl(u, h + 3), wo1_l[(h + 3) * HH + lane], c3);
        }
        const float v = fast_tanh((c0 + c1) + (c2 + c3));
        c0 = bo2; c1 = 0.f; c2 = 0.f; c3 = 0.f;
#pragma unroll
        for (int h = 0; h < HH; h += 4) {
            c0 = fmaf(rdl(v, h),     wo2_l[(h    ) * HH + lane], c0);
            c1 = fmaf(rdl(v, h + 1), wo2_l[(h + 1) * HH + lane], c1);
            c2 = fmaf(rdl(v, h + 2), wo2_l[(h + 2) * HH + lane], c2);
            c3 = fmaf(rdl(v, h + 3), wo2_l[(h + 3) * HH + lane], c3);
        }
        return fast_tanh((c0 + c1) + (c2 + c3));
    };

    // output head: p uniform across lanes after wave_sum; store directly.
    float* ob = out + (size_t)b * NN * TFC;
    {
        const float p = wave_sum(y * wo) + bo;     // traj[0] = hidden
        ob[lane * TFC]        = p;                 // n = lane
        ob[(64 + lane) * TFC] = p;                 // n = lane+64
    }

    const float dt = (float)(24.0 / 23.0);
    const float third = 1.f / 3.f;

#pragma unroll 1
    for (int st = 0; st < TFC - 1; ++st) {
        const float k1 = f_eval(y);
        const float k2 = f_eval(y + dt * k1 * third);
        const float k3 = f_eval(y + dt * (k2 - k1 * third));
        const float k4 = f_eval(y + dt * (k1 - k2 + k3));
        y = y + dt * (k1 + 3.f * (k2 + k3) + k4) * 0.125f;
        const float p = wave_sum(y * wo) + bo;
        ob[lane * TFC + st + 1]        = p;
        ob[(64 + lane) * TFC + st + 1] = p;
    }
}

extern "C" void kernel_launch(void* const* d_in, const int* in_sizes, int n_in,
                              void* d_out, int out_size, void* d_ws, size_t ws_size,
                              hipStream_t stream) {
    (void)in_sizes; (void)n_in; (void)d_ws; (void)ws_size; (void)out_size;
    const float* x    = (const float*)d_in[0];
    const float* Ws1  = (const float*)d_in[1];
    const float* bs1  = (const float*)d_in[2];
    const float* Ws2  = (const float*)d_in[3];
    const float* bs2  = (const float*)d_in[4];
    const float* Wa1  = (const float*)d_in[5];
    const float* ba1  = (const float*)d_in[6];
    const float* Wa2  = (const float*)d_in[7];
    // d_in[8]  = ba2  : unused (softmax shift-invariant)
    const float* Wih  = (const float*)d_in[9];
    // d_in[10] = W_hh : unused (h0 = 0)
    const float* bih  = (const float*)d_in[11];
    const float* bhh  = (const float*)d_in[12];
    const float* Wo1  = (const float*)d_in[13];
    const float* bo1  = (const float*)d_in[14];
    const float* Wo2  = (const float*)d_in[15];
    const float* bo2  = (const float*)d_in[16];
    const float* Wout = (const float*)d_in[17];
    const float* bout = (const float*)d_in[18];

    fused_kernel<<<dim3(BN), dim3(256), 0, stream>>>(
        x, Ws1, bs1, Ws2, bs2, Wa1, ba1, Wa2,
        Wih, bih, bhh, Wo1, bo1, Wo2, bo2, Wout, bout,
        (float*)d_out);
}